// Round 11
// baseline (120.854 us; speedup 1.0000x reference)
//
#include <hip/hip_runtime.h>

// KNRM forward, MI355X (gfx950). R10.
// R9 post-mortem: occupancy rose, dur flat -> not occupancy/latency-bound; the
// gather path is THROUGHPUT-saturated (153MB L2-miss at ~1.45TB/s random-256B
// pattern; per-block wall ~50us vs ~3us issue = queuing). R10 attacks the
// pattern: (1) hi|lo interleaved into ONE 512B-contiguous row per token
// (half the random granules, 2x granule size); (2) ring-6 of 16-row chunks,
// depth-5 prefetch (vmcnt(8) steady, 10 loads/wave queued) and ONE barrier per
// chunk (slot (c+5)%6=(c-1)%6 was freed at the previous iteration's barrier).
// Math identical to R6-R9 (absmax 0.0039).

typedef __attribute__((ext_vector_type(8))) short bf16x8;
typedef __attribute__((ext_vector_type(4))) float f32x4;
typedef __attribute__((ext_vector_type(2))) float f32x2;

__device__ __forceinline__ unsigned short f2bf(float f) {   // RNE float->bf16
    unsigned u = __float_as_uint(f);
    u += 0x7fffu + ((u >> 16) & 1u);
    return (unsigned short)(u >> 16);
}
__device__ __forceinline__ float bf2f(unsigned short h) {
    return __uint_as_float(((unsigned)h) << 16);
}

// ---- precompute: normalized bf16 hi|lo interleaved table [vocab][256] ----
// row layout: [0:128) = hi, [128:256) = lo  (one contiguous 512B region/row)
__global__ __launch_bounds__(256)
void norm_split_kernel(const float* __restrict__ emb,
                       unsigned short* __restrict__ tab, int vocab)
{
    const int row = blockIdx.x * 8 + (threadIdx.x >> 5);
    if (row >= vocab) return;
    const int ln = threadIdx.x & 31;
    const float4 v = *reinterpret_cast<const float4*>(emb + (size_t)row * 128 + ln * 4);
    float ss = v.x*v.x + v.y*v.y + v.z*v.z + v.w*v.w;
    #pragma unroll
    for (int m = 16; m >= 1; m >>= 1) ss += __shfl_xor(ss, m);
    const float rn = 1.0f / (sqrtf(ss) + 1e-13f);                // reference eps
    const float f0 = v.x*rn, f1 = v.y*rn, f2 = v.z*rn, f3 = v.w*rn;
    const unsigned short h0 = f2bf(f0), h1 = f2bf(f1), h2 = f2bf(f2), h3 = f2bf(f3);
    const unsigned short g0 = f2bf(f0 - bf2f(h0)), g1 = f2bf(f1 - bf2f(h1));
    const unsigned short g2 = f2bf(f2 - bf2f(h2)), g3 = f2bf(f3 - bf2f(h3));
    unsigned short* base = tab + (size_t)row * 256 + ln * 4;
    *reinterpret_cast<uint2*>(base) =
        make_uint2((unsigned)h0 | ((unsigned)h1 << 16), (unsigned)h2 | ((unsigned)h3 << 16));
    *reinterpret_cast<uint2*>(base + 128) =
        make_uint2((unsigned)g0 | ((unsigned)g1 << 16), (unsigned)g2 | ((unsigned)g3 << 16));
}

// ---- global_load_lds: 16B/lane, linear LDS dest (base + lane*16) ----
__device__ __forceinline__ void glds16(const unsigned short* g, unsigned short* l) {
    __builtin_amdgcn_global_load_lds((const __attribute__((address_space(1))) void*)g,
                                     (__attribute__((address_space(3))) void*)l, 16, 0, 0);
}

// Stage one 16-row chunk (wave w: rows 4w..4w+3 -> glds hi + glds lo, SAME 512B row).
// Swizzle folded into per-lane GLOBAL address: buffer slot s holds chunk s^r.
__device__ __forceinline__ void stage_d16(const unsigned short* __restrict__ tab,
                                          const int* __restrict__ ids, int base,
                                          unsigned short* __restrict__ dh,
                                          unsigned short* __restrict__ dl,
                                          int w, int l)
{
    const int r   = 4*w + (l >> 4);                  // buffer row 0..15
    const int id  = ids[base + r];                   // LDS broadcast read
    const int gsw = ((l & 15) ^ r) << 3;             // swizzled elem offset in row
    const unsigned short* g = tab + (size_t)id * 256 + gsw;
    glds16(g,       dh + 4*w * 128);                 // hi half
    glds16(g + 128, dl + 4*w * 128);                 // lo half (same 512B region)
}

// Stage q: wave w fills ring buffer w with its 16 q rows.
__device__ __forceinline__ void stage_q16(const unsigned short* __restrict__ tab,
                                          const int* __restrict__ qids,
                                          unsigned short* __restrict__ dh,
                                          unsigned short* __restrict__ dl,
                                          int w, int l)
{
    #pragma unroll
    for (int j = 0; j < 4; j++) {
        const int r   = 4*j + (l >> 4);
        const int id  = qids[16*w + r];
        const int gsw = ((l & 15) ^ r) << 3;
        const unsigned short* g = tab + (size_t)id * 256 + gsw;
        glds16(g,       dh + 4*j * 128);
        glds16(g + 128, dl + 4*j * 128);
    }
}

#define PKF(a, b, c) __builtin_elementwise_fma((a), (b), (c))

// 21 kernel contributions of an element PAIR (m0,m1); sp[i] packed {elem0, elem1}.
// Geometric ladder: k_{10+j} = t0*R^j*e^{-j(j+1)/2}, k_{10-j} = t0*R^-j*e^{-j(j-1)/2}.
__device__ __forceinline__ void apply_pair(float m0, float m1, f32x2 (&sp)[21]) {
    const f32x2 m2 = {m0, m1};
    const f32x2 dm = m2 - 0.05f;
    const f32x2 ta = (dm * dm) * -72.13475204444817f;            // -50*log2e*(m-.05)^2
    const f32x2 x2 = m2 * 14.426950408889634f;                   // 10*log2e*m
    const f32x2 t0 = { __builtin_amdgcn_exp2f(ta[0]), __builtin_amdgcn_exp2f(ta[1]) };
    const f32x2 R  = { __builtin_amdgcn_exp2f(x2[0]), __builtin_amdgcn_exp2f(x2[1]) };
    const f32x2 Ri = { __builtin_amdgcn_exp2f(-x2[0]), __builtin_amdgcn_exp2f(-x2[1]) };
    sp[10] += t0;
    f32x2 tu = t0;
    tu *= R;  sp[11] = PKF(tu, (f32x2)3.6787944117e-1f,  sp[11]);
    tu *= R;  sp[12] = PKF(tu, (f32x2)4.9787068368e-2f,  sp[12]);
    tu *= R;  sp[13] = PKF(tu, (f32x2)2.4787521767e-3f,  sp[13]);
    tu *= R;  sp[14] = PKF(tu, (f32x2)4.5399929762e-5f,  sp[14]);
    tu *= R;  sp[15] = PKF(tu, (f32x2)3.0590232050e-7f,  sp[15]);
    tu *= R;  sp[16] = PKF(tu, (f32x2)7.5825604279e-10f, sp[16]);
    tu *= R;  sp[17] = PKF(tu, (f32x2)6.9144001069e-13f, sp[17]);
    tu *= R;  sp[18] = PKF(tu, (f32x2)2.3195228302e-16f, sp[18]);
    tu *= R;  sp[19] = PKF(tu, (f32x2)2.8625185805e-20f, sp[19]);
    f32x2 td = t0;
    td *= Ri; sp[9] += td;
    td *= Ri; sp[8] = PKF(td, (f32x2)3.6787944117e-1f,  sp[8]);
    td *= Ri; sp[7] = PKF(td, (f32x2)4.9787068368e-2f,  sp[7]);
    td *= Ri; sp[6] = PKF(td, (f32x2)2.4787521767e-3f,  sp[6]);
    td *= Ri; sp[5] = PKF(td, (f32x2)4.5399929762e-5f,  sp[5]);
    td *= Ri; sp[4] = PKF(td, (f32x2)3.0590232050e-7f,  sp[4]);
    td *= Ri; sp[3] = PKF(td, (f32x2)7.5825604279e-10f, sp[3]);
    td *= Ri; sp[2] = PKF(td, (f32x2)6.9144001069e-13f, sp[2]);
    td *= Ri; sp[1] = PKF(td, (f32x2)2.3195228302e-16f, sp[1]);
    td *= Ri; sp[0] = PKF(td, (f32x2)2.8625185805e-20f, sp[0]);
    const f32x2 e  = m2 - 1.0f;                                    // exact-match (sigma=1e-3)
    const f32x2 ea = (e * e) * -721347.5204444817f;
    const f32x2 ex = { __builtin_amdgcn_exp2f(ea[0]), __builtin_amdgcn_exp2f(ea[1]) };
    sp[20] += ex;
}

#define MFMA(a, b, c) __builtin_amdgcn_mfma_f32_16x16x32_bf16((a), (b), (c), 0, 0, 0)

// ---- main kernel: one block per (batch, pass); ring-6 of 16-row chunks ----
__global__ __launch_bounds__(256, 2)
void knrm_main(const int* __restrict__ q1, const int* __restrict__ d1,
               const int* __restrict__ q2, const int* __restrict__ d2,
               const unsigned short* __restrict__ tab,
               float* __restrict__ kmws)
{
    __shared__ unsigned short bh[6][16*128];   // 4KB each (hi)
    __shared__ unsigned short bl[6][16*128];   // 4KB each (lo)
    __shared__ int   sh_ids[256];
    __shared__ float KMpart[4][21];

    const int tid = threadIdx.x;
    const int bb  = blockIdx.x >> 1;
    const int p   = blockIdx.x & 1;
    const int w   = tid >> 6;     // wave 0..3 -> q rows 16w..16w+15
    const int l   = tid & 63;
    const int lr  = l & 15;       // MFMA row (A) / col=q (B,C)
    const int lh  = l >> 4;       // k-group

    const int* qids = (p == 0 ? q1 : q2) + bb * 64;
    const int* dids = (p == 0 ? d1 : d2) + bb * 256;

    sh_ids[tid] = dids[tid];
    stage_q16(tab, qids, bh[w], bl[w], w, l);        // buf w = wave w's q rows
    asm volatile("s_waitcnt vmcnt(0) lgkmcnt(0)" ::: "memory");
    __builtin_amdgcn_s_barrier();                    // q + sh_ids visible to all

    // Hoist B (q-side) fragments to registers for the whole pass.
    bf16x8 Bh[4], Bl[4];
    #pragma unroll
    for (int ks = 0; ks < 4; ks++) {
        const int off = lr*128 + (((ks*4 + lh) ^ lr) << 3);
        Bh[ks] = *reinterpret_cast<const bf16x8*>(&bh[w][off]);
        Bl[ks] = *reinterpret_cast<const bf16x8*>(&bl[w][off]);
    }
    asm volatile("s_waitcnt lgkmcnt(0)" ::: "memory");   // my B reads landed
    __builtin_amdgcn_s_barrier();                        // all waves done reading q

    f32x2 sp[21];
    #pragma unroll
    for (int i = 0; i < 21; i++) sp[i] = (f32x2){0.f, 0.f};

    // Prologue: chunks 0..4 in flight (10 loads/wave outstanding).
    stage_d16(tab, sh_ids, 0,  bh[0], bl[0], w, l);
    stage_d16(tab, sh_ids, 16, bh[1], bl[1], w, l);
    stage_d16(tab, sh_ids, 32, bh[2], bl[2], w, l);
    stage_d16(tab, sh_ids, 48, bh[3], bl[3], w, l);
    stage_d16(tab, sh_ids, 64, bh[4], bl[4], w, l);

    for (int c = 0; c < 16; c++) {
        // Wait for my chunk-c loads only (up to 4 chunks stay in flight).
        if (c <= 11)      asm volatile("s_waitcnt vmcnt(8)" ::: "memory");
        else if (c == 12) asm volatile("s_waitcnt vmcnt(6)" ::: "memory");
        else if (c == 13) asm volatile("s_waitcnt vmcnt(4)" ::: "memory");
        else if (c == 14) asm volatile("s_waitcnt vmcnt(2)" ::: "memory");
        else              asm volatile("s_waitcnt vmcnt(0)" ::: "memory");
        __builtin_amdgcn_s_barrier();                // chunk c staged by all waves
        // (single barrier: refill target slot (c+5)%6 == (c-1)%6 was freed by
        //  every wave before it passed THIS barrier -> no second barrier needed)

        const unsigned short* ch = bh[c % 6];
        const unsigned short* cl = bl[c % 6];
        f32x4 C = {0.f,0.f,0.f,0.f};
        #pragma unroll
        for (int ks = 0; ks < 4; ks++) {
            const int o = lr*128 + (((ks*4 + lh) ^ lr) << 3);
            const bf16x8 Ah = *reinterpret_cast<const bf16x8*>(ch + o);
            const bf16x8 Al = *reinterpret_cast<const bf16x8*>(cl + o);
            C = MFMA(Ah, Bh[ks], C);
            C = MFMA(Ah, Bl[ks], C);
            C = MFMA(Al, Bh[ks], C);
        }
        apply_pair(C[0], C[1], sp);
        apply_pair(C[2], C[3], sp);

        if (c <= 10)                                 // refill freed slot with chunk c+5
            stage_d16(tab, sh_ids, (c + 5) * 16, bh[(c + 5) % 6], bl[(c + 5) % 6], w, l);
    }

    // In-register reduction: q-col sum (xor16,32) -> log1p -> 16-group sum (xor1..8).
    #pragma unroll
    for (int i = 0; i < 21; i++) {
        float s = sp[i][0] + sp[i][1];
        s += __shfl_xor(s, 16);
        s += __shfl_xor(s, 32);
        float t = log1pf(s);
        t += __shfl_xor(t, 1);
        t += __shfl_xor(t, 2);
        t += __shfl_xor(t, 4);
        t += __shfl_xor(t, 8);
        if (l == 0) KMpart[w][i] = t;
    }
    __syncthreads();
    if (tid < 21)
        kmws[blockIdx.x * 21 + tid] = KMpart[0][tid] + KMpart[1][tid]
                                    + KMpart[2][tid] + KMpart[3][tid];
}

// ---- tiny MLP kernel: one block per batch element ----
__global__ __launch_bounds__(64)
void mlp_kernel(const float* __restrict__ kmws,
                const float* __restrict__ W1, const float* __restrict__ b1,
                const float* __restrict__ W2, const float* __restrict__ b2,
                const float* __restrict__ W3, const float* __restrict__ b3,
                float* __restrict__ out)
{
    __shared__ float KMs[2][21], x1s[2][10], x2s[2][5];
    const int tid = threadIdx.x;
    const int bb  = blockIdx.x;
    if (tid < 42) KMs[tid / 21][tid % 21] = kmws[(bb * 2 + tid / 21) * 21 + (tid % 21)];
    __syncthreads();
    if (tid < 10) {
        for (int p = 0; p < 2; p++) {
            float acc = b1[tid];
            #pragma unroll
            for (int i = 0; i < 21; i++) acc = fmaf(fmaxf(KMs[p][i], 0.0f), W1[i*10 + tid], acc);
            x1s[p][tid] = acc;
        }
    }
    __syncthreads();
    if (tid < 5) {
        for (int p = 0; p < 2; p++) {
            float acc = b2[tid];
            #pragma unroll
            for (int i = 0; i < 10; i++) acc = fmaf(fmaxf(x1s[p][i], 0.0f), W2[i*5 + tid], acc);
            x2s[p][tid] = acc;
        }
    }
    __syncthreads();
    if (tid == 0) {
        float lv[2];
        for (int p = 0; p < 2; p++) {
            float acc = b3[0];
            #pragma unroll
            for (int i = 0; i < 5; i++) acc = fmaf(fmaxf(x2s[p][i], 0.0f), W3[i], acc);
            lv[p] = acc;
        }
        out[bb] = 1.0f / (1.0f + expf(lv[1] - lv[0]));   // sigmoid(l1 - l2)
    }
}

// ---- fallback (ws too small): self-contained R6-style kernel ----
__device__ __forceinline__ void stage_f32(const float* __restrict__ emb,
                                          const int* __restrict__ ids,
                                          unsigned short* __restrict__ hi,
                                          unsigned short* __restrict__ lo,
                                          int tid)
{
    const int lg = tid >> 5;
    const int ln = tid & 31;
    #pragma unroll
    for (int i = 0; i < 4; i++) {
        const int row = i * 8 + lg;
        const int id  = ids[row];
        const float4 v = *reinterpret_cast<const float4*>(emb + (size_t)id * 128 + ln * 4);
        float ss = v.x*v.x + v.y*v.y + v.z*v.z + v.w*v.w;
        #pragma unroll
        for (int m = 16; m >= 1; m >>= 1) ss += __shfl_xor(ss, m);
        const float rn = 1.0f / (sqrtf(ss) + 1e-13f);
        const float f0 = v.x*rn, f1 = v.y*rn, f2 = v.z*rn, f3 = v.w*rn;
        const unsigned short h0 = f2bf(f0), h1 = f2bf(f1), h2 = f2bf(f2), h3 = f2bf(f3);
        const unsigned short g0 = f2bf(f0 - bf2f(h0)), g1 = f2bf(f1 - bf2f(h1));
        const unsigned short g2 = f2bf(f2 - bf2f(h2)), g3 = f2bf(f3 - bf2f(h3));
        const int off = row*128 + (((ln >> 1) ^ (row & 15)) << 3) + ((ln & 1) << 2);
        *reinterpret_cast<uint2*>(hi + off) =
            make_uint2((unsigned)h0 | ((unsigned)h1 << 16), (unsigned)h2 | ((unsigned)h3 << 16));
        *reinterpret_cast<uint2*>(lo + off) =
            make_uint2((unsigned)g0 | ((unsigned)g1 << 16), (unsigned)g2 | ((unsigned)g3 << 16));
    }
}

__global__ __launch_bounds__(256, 2)
void knrm_fallback(const int* __restrict__ q1, const int* __restrict__ d1,
                   const int* __restrict__ q2, const int* __restrict__ d2,
                   const float* __restrict__ emb,
                   const float* __restrict__ W1, const float* __restrict__ b1,
                   const float* __restrict__ W2, const float* __restrict__ b2,
                   const float* __restrict__ W3, const float* __restrict__ b3,
                   float* __restrict__ out)
{
    __shared__ unsigned short bh[2][32*128], bl[2][32*128];
    __shared__ float KMpart[2][4][21];
    __shared__ float x1s[2][10], x2s[2][5];
    const int tid = threadIdx.x;
    const int bb  = blockIdx.x;
    const int w   = tid >> 6;
    const int l   = tid & 63;
    const int lr  = l & 15;
    const int lh  = l >> 4;

    for (int p = 0; p < 2; p++) {
        const int* qids = (p == 0 ? q1 : q2) + bb * 64;
        const int* dids = (p == 0 ? d1 : d2) + bb * 256;
        stage_f32(emb, qids,      bh[0], bl[0], tid);
        stage_f32(emb, qids + 32, bh[1], bl[1], tid);
        __syncthreads();
        bf16x8 Bh[4], Bl[4];
        const int qb = w >> 1;
        const int qr = (w * 16 + lr) & 31;
        #pragma unroll
        for (int ks = 0; ks < 4; ks++) {
            const int off = qr*128 + (((ks*4 + lh) ^ lr) << 3);
            Bh[ks] = *reinterpret_cast<const bf16x8*>(&bh[qb][off]);
            Bl[ks] = *reinterpret_cast<const bf16x8*>(&bl[qb][off]);
        }
        __syncthreads();
        f32x2 sp[21];
        #pragma unroll
        for (int i = 0; i < 21; i++) sp[i] = (f32x2){0.f, 0.f};
        for (int c = 0; c < 8; c++) {
            stage_f32(emb, dids + c * 32, bh[c & 1], bl[c & 1], tid);
            __syncthreads();
            const unsigned short* ch = bh[c & 1];
            const unsigned short* cl = bl[c & 1];
            f32x4 C0 = {0.f,0.f,0.f,0.f}, C1 = {0.f,0.f,0.f,0.f};
            #pragma unroll
            for (int ks = 0; ks < 4; ks++) {
                const int o0 = lr*128        + (((ks*4 + lh) ^ lr) << 3);
                const int o1 = (16 + lr)*128 + (((ks*4 + lh) ^ lr) << 3);
                const bf16x8 A0h = *reinterpret_cast<const bf16x8*>(ch + o0);
                const bf16x8 A0l = *reinterpret_cast<const bf16x8*>(cl + o0);
                const bf16x8 A1h = *reinterpret_cast<const bf16x8*>(ch + o1);
                const bf16x8 A1l = *reinterpret_cast<const bf16x8*>(cl + o1);
                C0 = MFMA(A0h, Bh[ks], C0); C1 = MFMA(A1h, Bh[ks], C1);
                C0 = MFMA(A0h, Bl[ks], C0); C1 = MFMA(A1h, Bl[ks], C1);
                C0 = MFMA(A0l, Bh[ks], C0); C1 = MFMA(A1l, Bh[ks], C1);
            }
            #pragma unroll
            for (int r = 0; r < 4; r++) apply_pair(C0[r], C1[r], sp);
            __syncthreads();
        }
        #pragma unroll
        for (int i = 0; i < 21; i++) {
            float s = sp[i][0] + sp[i][1];
            s += __shfl_xor(s, 16);
            s += __shfl_xor(s, 32);
            float t = log1pf(s);
            t += __shfl_xor(t, 1);
            t += __shfl_xor(t, 2);
            t += __shfl_xor(t, 4);
            t += __shfl_xor(t, 8);
            if (l == 0) KMpart[p][w][i] = t;
        }
    }
    __syncthreads();
    if (tid < 10) {
        for (int p = 0; p < 2; p++) {
            float acc = b1[tid];
            #pragma unroll
            for (int i = 0; i < 21; i++) {
                const float km = KMpart[p][0][i] + KMpart[p][1][i]
                               + KMpart[p][2][i] + KMpart[p][3][i];
                acc = fmaf(fmaxf(km, 0.0f), W1[i*10 + tid], acc);
            }
            x1s[p][tid] = acc;
        }
    }
    __syncthreads();
    if (tid < 5) {
        for (int p = 0; p < 2; p++) {
            float acc = b2[tid];
            #pragma unroll
            for (int i = 0; i < 10; i++) acc = fmaf(fmaxf(x1s[p][i], 0.0f), W2[i*5 + tid], acc);
            x2s[p][tid] = acc;
        }
    }
    __syncthreads();
    if (tid == 0) {
        float lv[2];
        for (int p = 0; p < 2; p++) {
            float acc = b3[0];
            #pragma unroll
            for (int i = 0; i < 5; i++) acc = fmaf(fmaxf(x2s[p][i], 0.0f), W3[i], acc);
            lv[p] = acc;
        }
        out[bb] = 1.0f / (1.0f + expf(lv[1] - lv[0]));
    }
}

extern "C" void kernel_launch(void* const* d_in, const int* in_sizes, int n_in,
                              void* d_out, int out_size, void* d_ws, size_t ws_size,
                              hipStream_t stream)
{
    const int*   q1  = (const int*)  d_in[0];
    const int*   d1  = (const int*)  d_in[1];
    const int*   q2  = (const int*)  d_in[2];
    const int*   d2  = (const int*)  d_in[3];
    const float* emb = (const float*)d_in[4];
    const float* W1  = (const float*)d_in[5];
    const float* b1  = (const float*)d_in[6];
    const float* W2  = (const float*)d_in[7];
    const float* b2  = (const float*)d_in[8];
    const float* W3  = (const float*)d_in[9];
    const float* b3  = (const float*)d_in[10];
    float* out = (float*)d_out;
    (void)n_in;

    const int    vocab = in_sizes[4] / 128;
    const size_t tabsz = (size_t)vocab * 256 * 2;        // interleaved hi|lo table
    const size_t kmsz  = (size_t)out_size * 2 * 21 * 4;  // KM partials
    const size_t need  = tabsz + kmsz;

    if (ws_size >= need) {
        unsigned short* tab = (unsigned short*)d_ws;
        float* kmws = (float*)((char*)d_ws + tabsz);
        norm_split_kernel<<<(vocab + 7) / 8, 256, 0, stream>>>(emb, tab, vocab);
        knrm_main<<<out_size * 2, 256, 0, stream>>>(q1, d1, q2, d2, tab, kmws);
        mlp_kernel<<<out_size, 64, 0, stream>>>(kmws, W1, b1, W2, b2, W3, b3, out);
    } else {
        knrm_fallback<<<out_size, 256, 0, stream>>>(q1, d1, q2, d2, emb,
                                                    W1, b1, W2, b2, W3, b3, out);
    }
}

// Round 12
// 104.515 us; speedup vs baseline: 1.1563x; 1.1563x over previous
//
#include <hip/hip_runtime.h>

// KNRM forward, MI355X (gfx950). R11.
// R9/R10 post-mortem: occupancy +24%, 512B granules, depth-5 queue, half the
// barriers -- ALL flat at ~108us, FETCH pinned 153MB @1.45TB/s: the gather path
// is throughput-saturated. Only bytes move a saturated path. R11: single fp16
// table (rel err 2.4e-4 -> M err ~2.2e-5 ~= the bf16-split's quality; at exact-
// match q,d read the SAME row so m=|q16|^2=1+-5e-5). Halves staged bytes
// (335->168MB), table 51->25.6MB (L3-resident), MFMA/chunk 12->4, LDS ring
// 48->24KB. Ring-6, single barrier/chunk, vmcnt(4) steady (1 load/chunk/wave).

typedef __attribute__((ext_vector_type(8))) _Float16 f16x8;
typedef __attribute__((ext_vector_type(4))) float f32x4;
typedef __attribute__((ext_vector_type(2))) float f32x2;

__device__ __forceinline__ unsigned short h2s(_Float16 h) {
    return __builtin_bit_cast(unsigned short, h);
}

// ---- precompute: normalized fp16 table, row-major [vocab][128] (256B/row) ----
__global__ __launch_bounds__(256)
void norm_split_kernel(const float* __restrict__ emb,
                       unsigned short* __restrict__ tab, int vocab)
{
    const int row = blockIdx.x * 8 + (threadIdx.x >> 5);
    if (row >= vocab) return;
    const int ln = threadIdx.x & 31;
    const float4 v = *reinterpret_cast<const float4*>(emb + (size_t)row * 128 + ln * 4);
    float ss = v.x*v.x + v.y*v.y + v.z*v.z + v.w*v.w;
    #pragma unroll
    for (int m = 16; m >= 1; m >>= 1) ss += __shfl_xor(ss, m);   // 32-lane row reduce
    const float rn = 1.0f / (sqrtf(ss) + 1e-13f);                // reference eps
    const unsigned short h0 = h2s((_Float16)(v.x * rn));
    const unsigned short h1 = h2s((_Float16)(v.y * rn));
    const unsigned short h2 = h2s((_Float16)(v.z * rn));
    const unsigned short h3 = h2s((_Float16)(v.w * rn));
    *reinterpret_cast<uint2*>(tab + (size_t)row * 128 + ln * 4) =
        make_uint2((unsigned)h0 | ((unsigned)h1 << 16), (unsigned)h2 | ((unsigned)h3 << 16));
}

// ---- global_load_lds: 16B/lane, linear LDS dest (base + lane*16) ----
__device__ __forceinline__ void glds16(const unsigned short* g, unsigned short* l) {
    __builtin_amdgcn_global_load_lds((const __attribute__((address_space(1))) void*)g,
                                     (__attribute__((address_space(3))) void*)l, 16, 0, 0);
}

// Stage one 16-row chunk (wave w: rows 4w..4w+3 -> ONE glds16).
// Swizzle folded into per-lane GLOBAL address: buffer group slot s holds group s^r.
__device__ __forceinline__ void stage_d16(const unsigned short* __restrict__ tab,
                                          const int* __restrict__ ids, int base,
                                          unsigned short* __restrict__ db,
                                          int w, int l)
{
    const int r   = 4*w + (l >> 4);                  // buffer row 0..15
    const int id  = ids[base + r];                   // LDS broadcast read
    const int gsw = ((l & 15) ^ r) << 3;             // swizzled elem offset in row
    glds16(tab + (size_t)id * 128 + gsw, db + 4*w * 128);
}

// Stage q: wave w fills one ring buffer with its 16 q rows (4 glds16).
__device__ __forceinline__ void stage_q16(const unsigned short* __restrict__ tab,
                                          const int* __restrict__ qids,
                                          unsigned short* __restrict__ db,
                                          int w, int l)
{
    #pragma unroll
    for (int j = 0; j < 4; j++) {
        const int r   = 4*j + (l >> 4);
        const int id  = qids[16*w + r];
        const int gsw = ((l & 15) ^ r) << 3;
        glds16(tab + (size_t)id * 128 + gsw, db + 4*j * 128);
    }
}

#define PKF(a, b, c) __builtin_elementwise_fma((a), (b), (c))

// 21 kernel contributions of an element PAIR (m0,m1); sp[i] packed {elem0, elem1}.
// Geometric ladder: k_{10+j} = t0*R^j*e^{-j(j+1)/2}, k_{10-j} = t0*R^-j*e^{-j(j-1)/2}.
__device__ __forceinline__ void apply_pair(float m0, float m1, f32x2 (&sp)[21]) {
    const f32x2 m2 = {m0, m1};
    const f32x2 dm = m2 - 0.05f;
    const f32x2 ta = (dm * dm) * -72.13475204444817f;            // -50*log2e*(m-.05)^2
    const f32x2 x2 = m2 * 14.426950408889634f;                   // 10*log2e*m
    const f32x2 t0 = { __builtin_amdgcn_exp2f(ta[0]), __builtin_amdgcn_exp2f(ta[1]) };
    const f32x2 R  = { __builtin_amdgcn_exp2f(x2[0]), __builtin_amdgcn_exp2f(x2[1]) };
    const f32x2 Ri = { __builtin_amdgcn_exp2f(-x2[0]), __builtin_amdgcn_exp2f(-x2[1]) };
    sp[10] += t0;
    f32x2 tu = t0;
    tu *= R;  sp[11] = PKF(tu, (f32x2)3.6787944117e-1f,  sp[11]);
    tu *= R;  sp[12] = PKF(tu, (f32x2)4.9787068368e-2f,  sp[12]);
    tu *= R;  sp[13] = PKF(tu, (f32x2)2.4787521767e-3f,  sp[13]);
    tu *= R;  sp[14] = PKF(tu, (f32x2)4.5399929762e-5f,  sp[14]);
    tu *= R;  sp[15] = PKF(tu, (f32x2)3.0590232050e-7f,  sp[15]);
    tu *= R;  sp[16] = PKF(tu, (f32x2)7.5825604279e-10f, sp[16]);
    tu *= R;  sp[17] = PKF(tu, (f32x2)6.9144001069e-13f, sp[17]);
    tu *= R;  sp[18] = PKF(tu, (f32x2)2.3195228302e-16f, sp[18]);
    tu *= R;  sp[19] = PKF(tu, (f32x2)2.8625185805e-20f, sp[19]);
    f32x2 td = t0;
    td *= Ri; sp[9] += td;
    td *= Ri; sp[8] = PKF(td, (f32x2)3.6787944117e-1f,  sp[8]);
    td *= Ri; sp[7] = PKF(td, (f32x2)4.9787068368e-2f,  sp[7]);
    td *= Ri; sp[6] = PKF(td, (f32x2)2.4787521767e-3f,  sp[6]);
    td *= Ri; sp[5] = PKF(td, (f32x2)4.5399929762e-5f,  sp[5]);
    td *= Ri; sp[4] = PKF(td, (f32x2)3.0590232050e-7f,  sp[4]);
    td *= Ri; sp[3] = PKF(td, (f32x2)7.5825604279e-10f, sp[3]);
    td *= Ri; sp[2] = PKF(td, (f32x2)6.9144001069e-13f, sp[2]);
    td *= Ri; sp[1] = PKF(td, (f32x2)2.3195228302e-16f, sp[1]);
    td *= Ri; sp[0] = PKF(td, (f32x2)2.8625185805e-20f, sp[0]);
    const f32x2 e  = m2 - 1.0f;                                    // exact-match (sigma=1e-3)
    const f32x2 ea = (e * e) * -721347.5204444817f;
    const f32x2 ex = { __builtin_amdgcn_exp2f(ea[0]), __builtin_amdgcn_exp2f(ea[1]) };
    sp[20] += ex;
}

// ---- main kernel: one block per (batch, pass); ring-6 of fp16 16-row chunks ----
__global__ __launch_bounds__(256, 2)
void knrm_main(const int* __restrict__ q1, const int* __restrict__ d1,
               const int* __restrict__ q2, const int* __restrict__ d2,
               const unsigned short* __restrict__ tab,
               float* __restrict__ kmws)
{
    __shared__ unsigned short buf[6][16*128];  // 4KB each (fp16 rows)
    __shared__ int   sh_ids[256];
    __shared__ float KMpart[4][21];

    const int tid = threadIdx.x;
    const int bb  = blockIdx.x >> 1;
    const int p   = blockIdx.x & 1;
    const int w   = tid >> 6;     // wave 0..3 -> q rows 16w..16w+15
    const int l   = tid & 63;
    const int lr  = l & 15;       // MFMA row (A) / col=q (B,C)
    const int lh  = l >> 4;       // k-group

    const int* qids = (p == 0 ? q1 : q2) + bb * 64;
    const int* dids = (p == 0 ? d1 : d2) + bb * 256;

    sh_ids[tid] = dids[tid];
    stage_q16(tab, qids, buf[w], w, l);              // buf w = wave w's q rows
    asm volatile("s_waitcnt vmcnt(0) lgkmcnt(0)" ::: "memory");
    __builtin_amdgcn_s_barrier();                    // q + sh_ids visible to all

    // Hoist B (q-side) fragments to registers for the whole pass.
    f16x8 Bq[4];
    #pragma unroll
    for (int ks = 0; ks < 4; ks++) {
        const int off = lr*128 + (((ks*4 + lh) ^ lr) << 3);
        Bq[ks] = *reinterpret_cast<const f16x8*>(&buf[w][off]);
    }
    asm volatile("s_waitcnt lgkmcnt(0)" ::: "memory");   // my B reads landed
    __builtin_amdgcn_s_barrier();                        // all waves done reading q

    f32x2 sp[21];
    #pragma unroll
    for (int i = 0; i < 21; i++) sp[i] = (f32x2){0.f, 0.f};

    // Prologue: chunks 0..4 in flight (5 loads/wave outstanding).
    stage_d16(tab, sh_ids, 0,  buf[0], w, l);
    stage_d16(tab, sh_ids, 16, buf[1], w, l);
    stage_d16(tab, sh_ids, 32, buf[2], w, l);
    stage_d16(tab, sh_ids, 48, buf[3], w, l);
    stage_d16(tab, sh_ids, 64, buf[4], w, l);

    for (int c = 0; c < 16; c++) {
        // Wait for my chunk-c load only (up to 4 later chunks stay in flight).
        if (c <= 11)      asm volatile("s_waitcnt vmcnt(4)" ::: "memory");
        else if (c == 12) asm volatile("s_waitcnt vmcnt(3)" ::: "memory");
        else if (c == 13) asm volatile("s_waitcnt vmcnt(2)" ::: "memory");
        else if (c == 14) asm volatile("s_waitcnt vmcnt(1)" ::: "memory");
        else              asm volatile("s_waitcnt vmcnt(0)" ::: "memory");
        __builtin_amdgcn_s_barrier();                // chunk c staged by all waves
        // (single barrier: refill slot (c+5)%6 == (c-1)%6 was freed by every
        //  wave before it passed THIS barrier)

        const unsigned short* cb = buf[c % 6];
        f32x4 C = {0.f,0.f,0.f,0.f};
        #pragma unroll
        for (int ks = 0; ks < 4; ks++) {
            const int o = lr*128 + (((ks*4 + lh) ^ lr) << 3);
            const f16x8 A = *reinterpret_cast<const f16x8*>(cb + o);
            C = __builtin_amdgcn_mfma_f32_16x16x32_f16(A, Bq[ks], C, 0, 0, 0);
        }
        apply_pair(C[0], C[1], sp);
        apply_pair(C[2], C[3], sp);

        if (c <= 10)                                 // refill freed slot with chunk c+5
            stage_d16(tab, sh_ids, (c + 5) * 16, buf[(c + 5) % 6], w, l);
    }

    // In-register reduction: q-col sum (xor16,32) -> log1p -> 16-group sum (xor1..8).
    #pragma unroll
    for (int i = 0; i < 21; i++) {
        float s = sp[i][0] + sp[i][1];
        s += __shfl_xor(s, 16);
        s += __shfl_xor(s, 32);
        float t = log1pf(s);
        t += __shfl_xor(t, 1);
        t += __shfl_xor(t, 2);
        t += __shfl_xor(t, 4);
        t += __shfl_xor(t, 8);
        if (l == 0) KMpart[w][i] = t;
    }
    __syncthreads();
    if (tid < 21)
        kmws[blockIdx.x * 21 + tid] = KMpart[0][tid] + KMpart[1][tid]
                                    + KMpart[2][tid] + KMpart[3][tid];
}

// ---- tiny MLP kernel: one block per batch element ----
__global__ __launch_bounds__(64)
void mlp_kernel(const float* __restrict__ kmws,
                const float* __restrict__ W1, const float* __restrict__ b1,
                const float* __restrict__ W2, const float* __restrict__ b2,
                const float* __restrict__ W3, const float* __restrict__ b3,
                float* __restrict__ out)
{
    __shared__ float KMs[2][21], x1s[2][10], x2s[2][5];
    const int tid = threadIdx.x;
    const int bb  = blockIdx.x;
    if (tid < 42) KMs[tid / 21][tid % 21] = kmws[(bb * 2 + tid / 21) * 21 + (tid % 21)];
    __syncthreads();
    if (tid < 10) {
        for (int p = 0; p < 2; p++) {
            float acc = b1[tid];
            #pragma unroll
            for (int i = 0; i < 21; i++) acc = fmaf(fmaxf(KMs[p][i], 0.0f), W1[i*10 + tid], acc);
            x1s[p][tid] = acc;
        }
    }
    __syncthreads();
    if (tid < 5) {
        for (int p = 0; p < 2; p++) {
            float acc = b2[tid];
            #pragma unroll
            for (int i = 0; i < 10; i++) acc = fmaf(fmaxf(x1s[p][i], 0.0f), W2[i*5 + tid], acc);
            x2s[p][tid] = acc;
        }
    }
    __syncthreads();
    if (tid == 0) {
        float lv[2];
        for (int p = 0; p < 2; p++) {
            float acc = b3[0];
            #pragma unroll
            for (int i = 0; i < 5; i++) acc = fmaf(fmaxf(x2s[p][i], 0.0f), W3[i], acc);
            lv[p] = acc;
        }
        out[bb] = 1.0f / (1.0f + expf(lv[1] - lv[0]));   // sigmoid(l1 - l2)
    }
}

// ---- fallback (ws too small): self-contained f32-gather kernel (bf16-split) ----
typedef __attribute__((ext_vector_type(8))) short bf16x8;
__device__ __forceinline__ unsigned short f2bf(float f) {
    unsigned u = __float_as_uint(f);
    u += 0x7fffu + ((u >> 16) & 1u);
    return (unsigned short)(u >> 16);
}
__device__ __forceinline__ float bf2f(unsigned short h) {
    return __uint_as_float(((unsigned)h) << 16);
}
__device__ __forceinline__ void stage_f32(const float* __restrict__ emb,
                                          const int* __restrict__ ids,
                                          unsigned short* __restrict__ hi,
                                          unsigned short* __restrict__ lo,
                                          int tid)
{
    const int lg = tid >> 5;
    const int ln = tid & 31;
    #pragma unroll
    for (int i = 0; i < 4; i++) {
        const int row = i * 8 + lg;
        const int id  = ids[row];
        const float4 v = *reinterpret_cast<const float4*>(emb + (size_t)id * 128 + ln * 4);
        float ss = v.x*v.x + v.y*v.y + v.z*v.z + v.w*v.w;
        #pragma unroll
        for (int m = 16; m >= 1; m >>= 1) ss += __shfl_xor(ss, m);
        const float rn = 1.0f / (sqrtf(ss) + 1e-13f);
        const float f0 = v.x*rn, f1 = v.y*rn, f2 = v.z*rn, f3 = v.w*rn;
        const unsigned short h0 = f2bf(f0), h1 = f2bf(f1), h2 = f2bf(f2), h3 = f2bf(f3);
        const unsigned short g0 = f2bf(f0 - bf2f(h0)), g1 = f2bf(f1 - bf2f(h1));
        const unsigned short g2 = f2bf(f2 - bf2f(h2)), g3 = f2bf(f3 - bf2f(h3));
        const int off = row*128 + (((ln >> 1) ^ (row & 15)) << 3) + ((ln & 1) << 2);
        *reinterpret_cast<uint2*>(hi + off) =
            make_uint2((unsigned)h0 | ((unsigned)h1 << 16), (unsigned)h2 | ((unsigned)h3 << 16));
        *reinterpret_cast<uint2*>(lo + off) =
            make_uint2((unsigned)g0 | ((unsigned)g1 << 16), (unsigned)g2 | ((unsigned)g3 << 16));
    }
}
#define MFMB(a, b, c) __builtin_amdgcn_mfma_f32_16x16x32_bf16((a), (b), (c), 0, 0, 0)

__global__ __launch_bounds__(256, 2)
void knrm_fallback(const int* __restrict__ q1, const int* __restrict__ d1,
                   const int* __restrict__ q2, const int* __restrict__ d2,
                   const float* __restrict__ emb,
                   const float* __restrict__ W1, const float* __restrict__ b1,
                   const float* __restrict__ W2, const float* __restrict__ b2,
                   const float* __restrict__ W3, const float* __restrict__ b3,
                   float* __restrict__ out)
{
    __shared__ unsigned short bh[2][32*128], bl[2][32*128];
    __shared__ float KMpart[2][4][21];
    __shared__ float x1s[2][10], x2s[2][5];
    const int tid = threadIdx.x;
    const int bb  = blockIdx.x;
    const int w   = tid >> 6;
    const int l   = tid & 63;
    const int lr  = l & 15;
    const int lh  = l >> 4;

    for (int p = 0; p < 2; p++) {
        const int* qids = (p == 0 ? q1 : q2) + bb * 64;
        const int* dids = (p == 0 ? d1 : d2) + bb * 256;
        stage_f32(emb, qids,      bh[0], bl[0], tid);
        stage_f32(emb, qids + 32, bh[1], bl[1], tid);
        __syncthreads();
        bf16x8 Bh[4], Bl[4];
        const int qb = w >> 1;
        const int qr = (w * 16 + lr) & 31;
        #pragma unroll
        for (int ks = 0; ks < 4; ks++) {
            const int off = qr*128 + (((ks*4 + lh) ^ lr) << 3);
            Bh[ks] = *reinterpret_cast<const bf16x8*>(&bh[qb][off]);
            Bl[ks] = *reinterpret_cast<const bf16x8*>(&bl[qb][off]);
        }
        __syncthreads();
        f32x2 sp[21];
        #pragma unroll
        for (int i = 0; i < 21; i++) sp[i] = (f32x2){0.f, 0.f};
        for (int c = 0; c < 8; c++) {
            stage_f32(emb, dids + c * 32, bh[c & 1], bl[c & 1], tid);
            __syncthreads();
            const unsigned short* ch = bh[c & 1];
            const unsigned short* cl = bl[c & 1];
            f32x4 C0 = {0.f,0.f,0.f,0.f}, C1 = {0.f,0.f,0.f,0.f};
            #pragma unroll
            for (int ks = 0; ks < 4; ks++) {
                const int o0 = lr*128        + (((ks*4 + lh) ^ lr) << 3);
                const int o1 = (16 + lr)*128 + (((ks*4 + lh) ^ lr) << 3);
                const bf16x8 A0h = *reinterpret_cast<const bf16x8*>(ch + o0);
                const bf16x8 A0l = *reinterpret_cast<const bf16x8*>(cl + o0);
                const bf16x8 A1h = *reinterpret_cast<const bf16x8*>(ch + o1);
                const bf16x8 A1l = *reinterpret_cast<const bf16x8*>(cl + o1);
                C0 = MFMB(A0h, Bh[ks], C0); C1 = MFMB(A1h, Bh[ks], C1);
                C0 = MFMB(A0h, Bl[ks], C0); C1 = MFMB(A1h, Bl[ks], C1);
                C0 = MFMB(A0l, Bh[ks], C0); C1 = MFMB(A1l, Bh[ks], C1);
            }
            #pragma unroll
            for (int r = 0; r < 4; r++) apply_pair(C0[r], C1[r], sp);
            __syncthreads();
        }
        #pragma unroll
        for (int i = 0; i < 21; i++) {
            float s = sp[i][0] + sp[i][1];
            s += __shfl_xor(s, 16);
            s += __shfl_xor(s, 32);
            float t = log1pf(s);
            t += __shfl_xor(t, 1);
            t += __shfl_xor(t, 2);
            t += __shfl_xor(t, 4);
            t += __shfl_xor(t, 8);
            if (l == 0) KMpart[p][w][i] = t;
        }
    }
    __syncthreads();
    if (tid < 10) {
        for (int p = 0; p < 2; p++) {
            float acc = b1[tid];
            #pragma unroll
            for (int i = 0; i < 21; i++) {
                const float km = KMpart[p][0][i] + KMpart[p][1][i]
                               + KMpart[p][2][i] + KMpart[p][3][i];
                acc = fmaf(fmaxf(km, 0.0f), W1[i*10 + tid], acc);
            }
            x1s[p][tid] = acc;
        }
    }
    __syncthreads();
    if (tid < 5) {
        for (int p = 0; p < 2; p++) {
            float acc = b2[tid];
            #pragma unroll
            for (int i = 0; i < 10; i++) acc = fmaf(fmaxf(x1s[p][i], 0.0f), W2[i*5 + tid], acc);
            x2s[p][tid] = acc;
        }
    }
    __syncthreads();
    if (tid == 0) {
        float lv[2];
        for (int p = 0; p < 2; p++) {
            float acc = b3[0];
            #pragma unroll
            for (int i = 0; i < 5; i++) acc = fmaf(fmaxf(x2s[p][i], 0.0f), W3[i], acc);
            lv[p] = acc;
        }
        out[bb] = 1.0f / (1.0f + expf(lv[1] - lv[0]));
    }
}

extern "C" void kernel_launch(void* const* d_in, const int* in_sizes, int n_in,
                              void* d_out, int out_size, void* d_ws, size_t ws_size,
                              hipStream_t stream)
{
    const int*   q1  = (const int*)  d_in[0];
    const int*   d1  = (const int*)  d_in[1];
    const int*   q2  = (const int*)  d_in[2];
    const int*   d2  = (const int*)  d_in[3];
    const float* emb = (const float*)d_in[4];
    const float* W1  = (const float*)d_in[5];
    const float* b1  = (const float*)d_in[6];
    const float* W2  = (const float*)d_in[7];
    const float* b2  = (const float*)d_in[8];
    const float* W3  = (const float*)d_in[9];
    const float* b3  = (const float*)d_in[10];
    float* out = (float*)d_out;
    (void)n_in;

    const int    vocab = in_sizes[4] / 128;
    const size_t tabsz = (size_t)vocab * 128 * 2;        // fp16 table bytes
    const size_t kmsz  = (size_t)out_size * 2 * 21 * 4;  // KM partials
    const size_t need  = tabsz + kmsz;

    if (ws_size >= need) {
        unsigned short* tab = (unsigned short*)d_ws;
        float* kmws = (float*)((char*)d_ws + tabsz);
        norm_split_kernel<<<(vocab + 7) / 8, 256, 0, stream>>>(emb, tab, vocab);
        knrm_main<<<out_size * 2, 256, 0, stream>>>(q1, d1, q2, d2, tab, kmws);
        mlp_kernel<<<out_size, 64, 0, stream>>>(kmws, W1, b1, W2, b2, W3, b3, out);
    } else {
        knrm_fallback<<<out_size, 256, 0, stream>>>(q1, d1, q2, d2, emb,
                                                    W1, b1, W2, b2, W3, b3, out);
    }
}